// Round 7
// baseline (2521.305 us; speedup 1.0000x reference)
//
#include <hip/hip_runtime.h>
#include <cfloat>

typedef unsigned short u16;
typedef unsigned int   u32;
typedef __attribute__((ext_vector_type(8))) short short8;
typedef __attribute__((ext_vector_type(4))) float float4_;

#define NB   2
#define N1   4096
#define N2   32768
#define C1   128
#define C2   64
#define CIN  192      // C1 + C2
#define F1   128
#define F2   128
#define ROW0 131      // 3 + C1 (fp32)
#define ROW1 67       // 3 + C2 (fp32)
#define NQ   (NB * N2)   // 65536 total query points
#define EPSF 1e-07f
#define PADX 200      // LDS x-tile pitch (u16)
#define PADH 136      // LDS h-tile pitch (u16)

// ---- spatial grid for kNN: 64^3 cells over [-8,8]^3 (N(0,1) data: nothing
// escapes +-8; P(|N|>8) ~ 6e-16). h=0.25 -> ~4 pts/cell at the density peak.
#define G     64
#define NC    (G * G * G)       // 262144 cells per batch
#define GLO   (-8.0f)
#define GH    0.25f
#define GHINV 4.0f
#define SCH   (NC / 1024)       // 256 cells per scan thread

// round-to-nearest-even fp32 -> bf16 (finite data only)
__device__ __forceinline__ u16 f2bf(float f) {
  u32 x = __float_as_uint(f);
  return (u16)((x + 0x7fffu + ((x >> 16) & 1u)) >> 16);
}

struct KW { int i0, i1, i2; float w0, w1, w2; };   // 24 B

// LEXICOGRAPHIC stable top-3 insert on (d, idx): exactly lax.top_k's tie rule
// (equal d -> smaller original index wins). Scan-order independent, which the
// grid path requires (cells are visited in spatial, not index, order).
__device__ __forceinline__ void lexins(float d, u32 gi,
    float& d0, float& d1, float& d2, u32& i0, u32& i1, u32& i2) {
  bool lt0 = (d < d0) || (d == d0 && gi < i0);
  bool lt1 = (d < d1) || (d == d1 && gi < i1);
  bool lt2 = (d < d2) || (d == d2 && gi < i2);
  d2 = lt1 ? d1 : (lt2 ? d : d2);  i2 = lt1 ? i1 : (lt2 ? gi : i2);
  d1 = lt0 ? d0 : (lt1 ? d : d1);  i1 = lt0 ? i0 : (lt1 ? gi : i1);
  d0 = lt0 ? d  : d0;              i0 = lt0 ? gi : i0;
}

__device__ __forceinline__ void cell_coords(float x, float y, float z,
                                            int& cx, int& cy, int& cz) {
  cx = (int)((x - GLO) * GHINV); cx = cx < 0 ? 0 : (cx > G - 1 ? G - 1 : cx);
  cy = (int)((y - GLO) * GHINV); cy = cy < 0 ? 0 : (cy > G - 1 ? G - 1 : cy);
  cz = (int)((z - GLO) * GHINV); cz = cz < 0 ? 0 : (cz > G - 1 ? G - 1 : cz);
}

// ---- repack weights (fp32 -> transposed bf16) + count points per grid cell ----
__global__ void repack_w(const float* __restrict__ W1, const float* __restrict__ W2,
                         u16* __restrict__ W1t, u16* __restrict__ W2t,
                         const float* __restrict__ in0, int* __restrict__ counts) {
  int i = blockIdx.x * 256 + threadIdx.x;
  if (i < F1 * CIN) { int n = i / CIN, k = i % CIN; W1t[i] = f2bf(W1[k * F1 + n]); }
  if (i < F2 * F1)  { int n = i / F1,  k = i % F1;  W2t[i] = f2bf(W2[k * F2 + n]); }
  if (i < NB * N1) {
    const float* r = in0 + (size_t)i * ROW0;
    int b = i >> 12;
    int cx, cy, cz; cell_coords(r[0], r[1], r[2], cx, cy, cz);
    atomicAdd(&counts[b * NC + ((cz << 12) | (cy << 6) | cx)], 1);
  }
}

// ---- exclusive scan of cell counts -> cell_start, and init cursor = start -----
// one 1024-thread block per batch; counts array is rewritten in-place as cursor.
__global__ __launch_bounds__(1024) void grid_scan(int* __restrict__ counts,
                                                  int* __restrict__ cell_start) {
  int b = blockIdx.x, t = threadIdx.x;
  int* cnt = counts + b * NC;
  int* cs  = cell_start + b * (NC + 1);
  __shared__ int ps[1024];
  int base = t * SCH;
  int sum = 0;
  for (int k = 0; k < SCH; k++) sum += cnt[base + k];
  ps[t] = sum; __syncthreads();
  for (int off = 1; off < 1024; off <<= 1) {   // Hillis-Steele inclusive
    int v = (t >= off) ? ps[t - off] : 0; __syncthreads();
    ps[t] += v; __syncthreads();
  }
  int run = ps[t] - sum;                        // exclusive offset
  for (int k = 0; k < SCH; k++) {
    int s = cnt[base + k];
    cs[base + k] = run; cnt[base + k] = run;    // cursor := start
    run += s;
  }
  if (t == 1023) cs[NC] = run;                  // = 4096
}

// ---- scatter points into cell-sorted order; .w carries the original index ----
__global__ void grid_scatter(const float* __restrict__ in0,
                             int* __restrict__ cursor, float4* __restrict__ xyzs) {
  int i = blockIdx.x * 256 + threadIdx.x;
  if (i >= NB * N1) return;
  const float* r = in0 + (size_t)i * ROW0;
  float x = r[0], y = r[1], z = r[2];
  int b = i >> 12, pi = i & (N1 - 1);
  int cx, cy, cz; cell_coords(x, y, z, cx, cy, cz);
  int pos = atomicAdd(&cursor[b * NC + ((cz << 12) | (cy << 6) | cx)], 1);
  float4 v; v.x = x; v.y = y; v.z = z; v.w = __uint_as_float((u32)pi);
  xyzs[b * N1 + pos] = v;
}

// ---- kNN via expanding-ring grid search; 4 threads cooperate per query -------
// Cells of each Chebyshev ring are dealt round-robin (counter & 3) to the 4
// sub-threads (identical skip sequence -> identical counters). Certified stop:
// (min distance from q to the unsearched region - 1e-5)^2 > d2. Any sub's
// certificate is valid for the combined result since own_d2 >= combined_d2;
// 4-lane ballot makes the break group-uniform. Distances use the exact
// reference RN sequence; lexicographic (d,idx) insert == lax.top_k tie rule.
__global__ __launch_bounds__(256) void knn_grid(
    const float* __restrict__ in1, const int* __restrict__ cell_start,
    const float4* __restrict__ xyzs, KW* __restrict__ kw,
    float* __restrict__ out) {
  int T = blockIdx.x * 256 + threadIdx.x;
  int q = T >> 2, sub = T & 3, lane = threadIdx.x & 63;
  int b = q >> 15, n = q & (N2 - 1);
  const float* qr = in1 + (size_t)(b * N2 + n) * ROW1;
  float qx = qr[0], qy = qr[1], qz = qr[2];
  if (sub == 1) {                               // xyz2 passthrough
    float* o = out + (size_t)NQ * F2 + (size_t)q * 3;
    o[0] = qx; o[1] = qy; o[2] = qz;
  }
  int cx, cy, cz; cell_coords(qx, qy, qz, cx, cy, cz);
  const int*    csb = cell_start + b * (NC + 1);
  const float4* xp  = xyzs + b * N1;
  float d0 = FLT_MAX, d1 = FLT_MAX, d2 = FLT_MAX;
  u32   i0 = 0x7fffffffu, i1 = 0x7fffffffu, i2 = 0x7fffffffu;
  int counter = 0;
  for (int r = 0; r <= G; ++r) {
    for (int dz = -r; dz <= r; ++dz) {
      int z = cz + dz; if ((unsigned)z >= G) continue;
      bool fz = (dz == -r) | (dz == r);
      for (int dy = -r; dy <= r; ++dy) {
        int y = cy + dy; if ((unsigned)y >= G) continue;
        bool fzy = fz | (dy == -r) | (dy == r);
        for (int dx = -r; dx <= r; ++dx) {
          if (!(fzy | (dx == -r) | (dx == r))) continue;   // ring-r cells only
          int x = cx + dx; if ((unsigned)x >= G) continue;
          if (((counter++) & 3) != sub) continue;
          int c = (z << 12) | (y << 6) | x;
          int s = csb[c], e = csb[c + 1];
          for (int j = s; j < e; ++j) {
            float4 pt = xp[j];
            float ddx = qx - pt.x, ddy = qy - pt.y, ddz = qz - pt.z;
            float d = __fadd_rn(__fadd_rn(__fmul_rn(ddx, ddx), __fmul_rn(ddy, ddy)),
                                __fmul_rn(ddz, ddz));
            lexins(d, __float_as_uint(pt.w), d0, d1, d2, i0, i1, i2);
          }
        }
      }
    }
    // certification: distance from q to the boundary of the searched cube
    float lox = GLO + (float)(cx - r) * GH, hix = GLO + (float)(cx + r + 1) * GH;
    float loy = GLO + (float)(cy - r) * GH, hiy = GLO + (float)(cy + r + 1) * GH;
    float loz = GLO + (float)(cz - r) * GH, hiz = GLO + (float)(cz + r + 1) * GH;
    float m = fminf(fminf(fminf(qx - lox, hix - qx), fminf(qy - loy, hiy - qy)),
                    fminf(qz - loz, hiz - qz)) - 1e-5f;   // margin >> fp slop
    bool cert = (m > 0.f) && (__fmul_rn(m, m) > d2);
    unsigned long long bal = __ballot(cert);
    if ((bal >> (lane & 60)) & 0xFULL) break;   // group-uniform break
  }
  // lex-merge the 4 partial top-3s (xor butterfly within the 4-lane group)
  for (int st = 1; st <= 2; st <<= 1) {
    float pd0 = __shfl_xor(d0, st), pd1 = __shfl_xor(d1, st), pd2 = __shfl_xor(d2, st);
    u32 pi0 = (u32)__shfl_xor((int)i0, st);
    u32 pi1 = (u32)__shfl_xor((int)i1, st);
    u32 pi2 = (u32)__shfl_xor((int)i2, st);
    lexins(pd0, pi0, d0, d1, d2, i0, i1, i2);
    lexins(pd1, pi1, d0, d1, d2, i0, i1, i2);
    lexins(pd2, pi2, d0, d1, d2, i0, i1, i2);
  }
  if (sub == 0) {
    float a0 = fmaxf(d0, EPSF), a1 = fmaxf(d1, EPSF), a2 = fmaxf(d2, EPSF);
    float w0 = 1.f / a0, w1 = 1.f / a1, w2 = 1.f / a2;
    float s = __fadd_rn(__fadd_rn(w0, w1), w2);
    KW o; o.i0 = (int)i0; o.i1 = (int)i1; o.i2 = (int)i2;
    o.w0 = w0 / s; o.w1 = w1 / s; o.w2 = w2 / s;
    kw[q] = o;
  }
}

// ---- K3: interp + concat -> bf16 LDS -> MFMA MLP1 -> MFMA MLP2 -> fp32 out -----
// block = 256 = 4 waves; each wave owns 16 query rows. 1024 blocks.
__global__ __launch_bounds__(256) void interp_mlp(
    const float* __restrict__ in0, const float* __restrict__ in1,
    const KW* __restrict__ kw,
    const u16* __restrict__ W1t, const float* __restrict__ b1,
    const u16* __restrict__ W2t, const float* __restrict__ b2,
    float* __restrict__ out) {
  __shared__ __align__(16) u16 xs[4][16][PADX];   // 25,600 B
  __shared__ __align__(16) u16 hs[4][16][PADH];   // 17,408 B
  int t = threadIdx.x;
  int wave = t >> 6, lane = t & 63;
  int l16 = lane & 15, quad = lane >> 4;
  int qbase = blockIdx.x * 64 + wave * 16;
  int b = qbase >> 15;                  // uniform per block

  // interp + concat into xs[wave] (16 x 192), fp32 gather, bf16 pack
  for (int qi = 0; qi < 16; qi++) {
    int q = qbase + qi;
    KW k = kw[q];                       // wave-uniform load
    const float* base = in0 + (size_t)b * N1 * ROW0 + 3;
    const float* r0 = base + (size_t)k.i0 * ROW0;
    const float* r1 = base + (size_t)k.i1 * ROW0;
    const float* r2 = base + (size_t)k.i2 * ROW0;
    float lo = __fadd_rn(__fadd_rn(__fmul_rn(k.w0, r0[lane]),
                                   __fmul_rn(k.w1, r1[lane])),
                         __fmul_rn(k.w2, r2[lane]));
    float hi = __fadd_rn(__fadd_rn(__fmul_rn(k.w0, r0[64 + lane]),
                                   __fmul_rn(k.w1, r1[64 + lane])),
                         __fmul_rn(k.w2, r2[64 + lane]));
    xs[wave][qi][lane]      = f2bf(lo);
    xs[wave][qi][64 + lane] = f2bf(hi);
    int n2 = q & (N2 - 1);              // channels 128..191 = points2
    xs[wave][qi][C1 + lane] = f2bf(in1[(size_t)(b * N2 + n2) * ROW1 + 3 + lane]);
  }
  __syncthreads();

  // GEMM1: h = relu(x @ W1 + b1); A from LDS, B from global (L1/L2-resident)
  float4_ acc[8];
#pragma unroll
  for (int nt = 0; nt < 8; nt++) acc[nt] = (float4_)0.f;
#pragma unroll
  for (int k0 = 0; k0 < CIN; k0 += 32) {
    short8 af = *(const short8*)&xs[wave][l16][k0 + quad * 8];
#pragma unroll
    for (int nt = 0; nt < 8; nt++) {
      short8 bf = *(const short8*)(W1t + (size_t)(nt * 16 + l16) * CIN + k0 + quad * 8);
      acc[nt] = __builtin_amdgcn_mfma_f32_16x16x32_bf16(af, bf, acc[nt], 0, 0, 0);
    }
  }
#pragma unroll
  for (int nt = 0; nt < 8; nt++) {
    float bv = b1[nt * 16 + l16];
#pragma unroll
    for (int r = 0; r < 4; r++) {   // C/D: row=quad*4+r, col=nt*16+l16
      hs[wave][quad * 4 + r][nt * 16 + l16] = f2bf(fmaxf(acc[nt][r] + bv, 0.f));
    }
  }
  __syncthreads();

  // GEMM2: y = relu(h @ W2 + b2) -> fp32 global store
  float4_ a2[8];
#pragma unroll
  for (int nt = 0; nt < 8; nt++) a2[nt] = (float4_)0.f;
#pragma unroll
  for (int k0 = 0; k0 < F1; k0 += 32) {
    short8 af = *(const short8*)&hs[wave][l16][k0 + quad * 8];
#pragma unroll
    for (int nt = 0; nt < 8; nt++) {
      short8 bf = *(const short8*)(W2t + (size_t)(nt * 16 + l16) * F1 + k0 + quad * 8);
      a2[nt] = __builtin_amdgcn_mfma_f32_16x16x32_bf16(af, bf, a2[nt], 0, 0, 0);
    }
  }
#pragma unroll
  for (int nt = 0; nt < 8; nt++) {
    float bv = b2[nt * 16 + l16];
#pragma unroll
    for (int r = 0; r < 4; r++) {
      int row = qbase + quad * 4 + r;
      out[(size_t)row * F2 + nt * 16 + l16] = fmaxf(a2[nt][r] + bv, 0.f);
    }
  }
}

extern "C" void kernel_launch(void* const* d_in, const int* in_sizes, int n_in,
                              void* d_out, int out_size, void* d_ws, size_t ws_size,
                              hipStream_t stream) {
  // input assignment by element count (ordering-invariant); positional fallback
  const float *in0 = nullptr, *in1 = nullptr, *W1 = nullptr, *W2 = nullptr;
  const float *b1 = nullptr, *b2 = nullptr;
  for (int i = 0; i < n_in; i++) {
    const float* p = (const float*)d_in[i];
    switch (in_sizes[i]) {
      case 2 * N1 * ROW0: in0 = p; break;
      case 2 * N2 * ROW1: in1 = p; break;
      case CIN * F1:      W1  = p; break;
      case F1 * F2:       W2  = p; break;
      case F1:            (b1 ? b2 : b1) = p; break;
      default: break;
    }
  }
  if (!in0) in0 = (const float*)d_in[0];
  if (!in1) in1 = (const float*)d_in[1];
  if (!W1)  W1  = (const float*)d_in[2];
  if (!b1)  b1  = (const float*)d_in[3];
  if (!W2)  W2  = (const float*)d_in[4];
  if (!b2)  b2  = (const float*)d_in[5];

  float* out = (float*)d_out;   // fp32: x (65536*128) ++ xyz2 (65536*3)

  // ws layout (5.98 MB total, well under proven 13.58 MB):
  //   W1t 49,152 | W2t 32,768 | kw 1,572,864 | cell_start 2,097,160 |
  //   cursor/counts 2,097,152 | xyzs 131,072
  char* ws = (char*)d_ws;
  u16*    W1t    = (u16*)(ws + 0);
  u16*    W2t    = (u16*)(ws + 49152);
  KW*     kw     = (KW*)(ws + 81920);
  int*    cstart = (int*)(ws + 1654784);
  int*    cursor = (int*)(ws + 3751952);
  float4* xyzs   = (float4*)(ws + 5849104);

  hipMemsetAsync(cursor, 0, (size_t)NB * NC * 4, stream);
  repack_w<<<dim3(96), dim3(256), 0, stream>>>(W1, W2, W1t, W2t, in0, cursor);
  grid_scan<<<dim3(NB), dim3(1024), 0, stream>>>(cursor, cstart);
  grid_scatter<<<dim3(32), dim3(256), 0, stream>>>(in0, cursor, xyzs);
  knn_grid<<<dim3(NQ * 4 / 256), dim3(256), 0, stream>>>(in1, cstart, xyzs, kw, out);
  interp_mlp<<<dim3(NQ / 64), dim3(256), 0, stream>>>(in0, in1, kw, W1t, b1, W2t, b2, out);
}

// Round 8
// 1779.099 us; speedup vs baseline: 1.4172x; 1.4172x over previous
//
#include <hip/hip_runtime.h>
#include <cfloat>

typedef unsigned short u16;
typedef unsigned int   u32;
typedef unsigned long long u64;
typedef __attribute__((ext_vector_type(8))) short short8;
typedef __attribute__((ext_vector_type(4))) float float4_;

#define NB   2
#define N1   4096
#define N2   32768
#define C1   128
#define C2   64
#define CIN  192      // C1 + C2
#define F1   128
#define F2   128
#define ROW0 131      // 3 + C1 (fp32)
#define ROW1 67       // 3 + C2 (fp32)
#define NQ   (NB * N2)   // 65536 total query points
#define EPSF 1e-07f
#define PADX 200      // LDS x-tile pitch (u16)
#define PADH 136      // LDS h-tile pitch (u16)

// ---- spatial grid: 64^3 cells over [-8,8]^3 (validated exact in R7) ----------
#define G     64
#define NC    (G * G * G)       // 262144 cells per batch
#define GLO   (-8.0f)
#define GH    0.25f
#define GHINV 4.0f
#define SCH   (NC / 1024)       // 256 cells per scan thread

// round-to-nearest-even fp32 -> bf16 (finite data only)
__device__ __forceinline__ u16 f2bf(float f) {
  u32 x = __float_as_uint(f);
  return (u16)((x + 0x7fffu + ((x >> 16) & 1u)) >> 16);
}

struct KW { int i0, i1, i2; float w0, w1, w2; };   // 24 B

// u64 key = (d_bits<<32)|idx : one u64 compare == lexicographic (d, idx) --
// exactly lax.top_k's tie rule (d ascending, then smaller original index).
// Insert is idempotent (equal key is not strictly <). Scan-order independent.
__device__ __forceinline__ void kins(u64 k, u64& k0, u64& k1, u64& k2) {
  bool lt0 = k < k0, lt1 = k < k1, lt2 = k < k2;
  k2 = lt1 ? k1 : (lt2 ? k : k2);
  k1 = lt0 ? k0 : (lt1 ? k : k1);
  k0 = lt0 ? k  : k0;
}

__device__ __forceinline__ void cell_coords(float x, float y, float z,
                                            int& cx, int& cy, int& cz) {
  cx = (int)((x - GLO) * GHINV); cx = cx < 0 ? 0 : (cx > G - 1 ? G - 1 : cx);
  cy = (int)((y - GLO) * GHINV); cy = cy < 0 ? 0 : (cy > G - 1 ? G - 1 : cy);
  cz = (int)((z - GLO) * GHINV); cz = cz < 0 ? 0 : (cz > G - 1 ? G - 1 : cz);
}

// ---- repack weights + count candidates AND queries per grid cell --------------
__global__ void repack_cnt(const float* __restrict__ W1, const float* __restrict__ W2,
                           u16* __restrict__ W1t, u16* __restrict__ W2t,
                           const float* __restrict__ in0, const float* __restrict__ in1,
                           int* __restrict__ ccnt, int* __restrict__ qcnt) {
  int i = blockIdx.x * 256 + threadIdx.x;
  if (i < F1 * CIN) { int n = i / CIN, k = i % CIN; W1t[i] = f2bf(W1[k * F1 + n]); }
  if (i < F2 * F1)  { int n = i / F1,  k = i % F1;  W2t[i] = f2bf(W2[k * F2 + n]); }
  if (i < NB * N1) {
    const float* r = in0 + (size_t)i * ROW0;
    int b = i >> 12;
    int cx, cy, cz; cell_coords(r[0], r[1], r[2], cx, cy, cz);
    atomicAdd(&ccnt[b * NC + ((cz << 12) | (cy << 6) | cx)], 1);
  }
  if (i < NB * N2) {
    int b = i >> 15, n = i & (N2 - 1);
    const float* r = in1 + (size_t)(b * N2 + n) * ROW1;
    int cx, cy, cz; cell_coords(r[0], r[1], r[2], cx, cy, cz);
    atomicAdd(&qcnt[b * NC + ((cz << 12) | (cy << 6) | cx)], 1);
  }
}

// ---- exclusive scan (validated R7 body, generalized to 4 arrays) --------------
// blockIdx: bit0 = batch, bit1 = which (0: candidates, 1: queries).
// counts array is rewritten in-place as the scatter cursor.
__global__ __launch_bounds__(1024) void grid_scan(int* __restrict__ ccnt,
                                                  int* __restrict__ cstart,
                                                  int* __restrict__ qcnt,
                                                  int* __restrict__ qstart) {
  int b = blockIdx.x & 1, which = blockIdx.x >> 1, t = threadIdx.x;
  int* cnt = (which ? qcnt : ccnt) + b * NC;
  int* cs  = (which ? qstart : cstart) + b * (NC + 1);
  __shared__ int ps[1024];
  int base = t * SCH;
  int sum = 0;
  for (int k = 0; k < SCH; k++) sum += cnt[base + k];
  ps[t] = sum; __syncthreads();
  for (int off = 1; off < 1024; off <<= 1) {   // Hillis-Steele inclusive
    int v = (t >= off) ? ps[t - off] : 0; __syncthreads();
    ps[t] += v; __syncthreads();
  }
  int run = ps[t] - sum;                        // exclusive offset
  for (int k = 0; k < SCH; k++) {
    int s = cnt[base + k];
    cs[base + k] = run; cnt[base + k] = run;    // cursor := start
    run += s;
  }
  if (t == 1023) cs[NC] = run;
}

// ---- scatter candidates (cell-sorted) + queries (cell-sorted) + passthrough ---
__global__ void scatter_all(const float* __restrict__ in0, const float* __restrict__ in1,
                            int* __restrict__ ccur, int* __restrict__ qcur,
                            float4* __restrict__ xyzs, float4* __restrict__ qxyz,
                            float* __restrict__ out) {
  int i = blockIdx.x * 256 + threadIdx.x;
  if (i < NB * N1) {
    const float* r = in0 + (size_t)i * ROW0;
    float x = r[0], y = r[1], z = r[2];
    int b = i >> 12, pi = i & (N1 - 1);
    int cx, cy, cz; cell_coords(x, y, z, cx, cy, cz);
    int pos = atomicAdd(&ccur[b * NC + ((cz << 12) | (cy << 6) | cx)], 1);
    float4 v; v.x = x; v.y = y; v.z = z; v.w = __uint_as_float((u32)pi);
    xyzs[b * N1 + pos] = v;
  } else if (i < NB * N1 + NB * N2) {
    int j = i - NB * N1;
    int b = j >> 15, n = j & (N2 - 1);
    const float* r = in1 + (size_t)(b * N2 + n) * ROW1;
    float x = r[0], y = r[1], z = r[2];
    float* o = out + (size_t)NQ * F2 + (size_t)(b * N2 + n) * 3;  // passthrough
    o[0] = x; o[1] = y; o[2] = z;
    int cx, cy, cz; cell_coords(x, y, z, cx, cy, cz);
    int pos = atomicAdd(&qcur[b * NC + ((cz << 12) | (cy << 6) | cx)], 1);
    float4 v; v.x = x; v.y = y; v.z = z; v.w = __uint_as_float((u32)n);
    qxyz[b * N2 + pos] = v;
  }
}

// scan one cell: deal by counter parity among 4 subs, then gather its points.
__device__ __forceinline__ void scan_cell(int x, int y, int z, int& counter, int sub,
    const int* __restrict__ csb, const float4* __restrict__ xp,
    float qx, float qy, float qz, u64& k0, u64& k1, u64& k2) {
  if (((counter++) & 3) != sub) return;
  if ((unsigned)x >= G || (unsigned)y >= G || (unsigned)z >= G) return;
  int c = (z << 12) | (y << 6) | x;
  int s = csb[c], e = csb[c + 1];
  for (int j = s; j < e; ++j) {
    float4 pt = xp[j];
    float dx = qx - pt.x, dy = qy - pt.y, dz = qz - pt.z;
    float d = __fadd_rn(__fadd_rn(__fmul_rn(dx, dx), __fmul_rn(dy, dy)),
                        __fmul_rn(dz, dz));             // exact reference order
    u64 k = ((u64)__float_as_uint(d) << 32) | (u32)__float_as_uint(pt.w);
    kins(k, k0, k1, k2);
  }
}

// ---- kNN: cell-sorted queries, 4 sub-lanes/query, direct surface enumeration --
// Queries sorted by cell -> waves hold spatially-adjacent queries (coherent
// rings, shared csb/point cache lines, balanced stop radii). Ring r visits
// exactly its 24r^2+2 surface cells (faces dz=+-r, rows dy=+-r, cols dx=+-r).
// Certification (validated R7): (dist to searched-cube boundary - 1e-5)^2 > d2,
// with d2 = min over the 4 subs (combined_d2 <= min of sub d2's). Full lex
// merge via 2-stage shfl butterfly at the end.
__global__ __launch_bounds__(256) void knn_grid(
    const int* __restrict__ cstart, const float4* __restrict__ xyzs,
    const float4* __restrict__ qxyz, KW* __restrict__ kw) {
  int T = blockIdx.x * 256 + threadIdx.x;
  int qs = T >> 2, sub = T & 3;
  int b = qs >> 15;
  float4 qv = qxyz[qs];
  float qx = qv.x, qy = qv.y, qz = qv.z;
  u32 n = __float_as_uint(qv.w);
  int cx, cy, cz; cell_coords(qx, qy, qz, cx, cy, cz);
  const int*    csb = cstart + b * (NC + 1);
  const float4* xp  = xyzs + b * N1;
  u64 k0 = 0x7F800000FFFFFFFFull, k1 = k0, k2 = k0;   // (inf, idx_max)
  bool done = false;
  for (int r = 0; r <= G; ++r) {
    if (!done) {
      int counter = 0;
      if (r == 0) {
        scan_cell(cx, cy, cz, counter, sub, csb, xp, qx, qy, qz, k0, k1, k2);
      } else {
        for (int dz = -r; dz <= r; dz += 2 * r)          // faces dz = +-r
          for (int dy = -r; dy <= r; ++dy)
            for (int dx = -r; dx <= r; ++dx)
              scan_cell(cx + dx, cy + dy, cz + dz, counter, sub, csb, xp, qx, qy, qz, k0, k1, k2);
        for (int dz = -r + 1; dz <= r - 1; ++dz) {       // interior slabs
          for (int dy = -r; dy <= r; dy += 2 * r)        // rows dy = +-r
            for (int dx = -r; dx <= r; ++dx)
              scan_cell(cx + dx, cy + dy, cz + dz, counter, sub, csb, xp, qx, qy, qz, k0, k1, k2);
          for (int dx = -r; dx <= r; dx += 2 * r)        // cols dx = +-r
            for (int dy = -r + 1; dy <= r - 1; ++dy)
              scan_cell(cx + dx, cy + dy, cz + dz, counter, sub, csb, xp, qx, qy, qz, k0, k1, k2);
        }
      }
    }
    // merged d2 bound across the 4 subs (combined_d2 <= min of sub d2's)
    float d2f = __uint_as_float((u32)(k2 >> 32));
    d2f = fminf(d2f, __shfl_xor(d2f, 1));
    d2f = fminf(d2f, __shfl_xor(d2f, 2));
    float lox = GLO + (float)(cx - r) * GH, hix = GLO + (float)(cx + r + 1) * GH;
    float loy = GLO + (float)(cy - r) * GH, hiy = GLO + (float)(cy + r + 1) * GH;
    float loz = GLO + (float)(cz - r) * GH, hiz = GLO + (float)(cz + r + 1) * GH;
    float m = fminf(fminf(fminf(qx - lox, hix - qx), fminf(qy - loy, hiy - qy)),
                    fminf(qz - loz, hiz - qz)) - 1e-5f;   // margin >> fp slop
    done = done || ((m > 0.f) && (__fmul_rn(m, m) > d2f));
    if (__ballot(!done) == 0ull) break;                   // wave-uniform
  }
  // full lex merge of the 4 partial top-3s
  for (int st = 1; st <= 2; st <<= 1) {
    u64 p0 = __shfl_xor(k0, st), p1 = __shfl_xor(k1, st), p2 = __shfl_xor(k2, st);
    kins(p0, k0, k1, k2); kins(p1, k0, k1, k2); kins(p2, k0, k1, k2);
  }
  if (sub == 0) {
    float d0 = __uint_as_float((u32)(k0 >> 32));
    float d1 = __uint_as_float((u32)(k1 >> 32));
    float d2 = __uint_as_float((u32)(k2 >> 32));
    float a0 = fmaxf(d0, EPSF), a1 = fmaxf(d1, EPSF), a2 = fmaxf(d2, EPSF);
    float w0 = 1.f / a0, w1 = 1.f / a1, w2 = 1.f / a2;
    float s = __fadd_rn(__fadd_rn(w0, w1), w2);
    KW o; o.i0 = (int)(u32)k0; o.i1 = (int)(u32)k1; o.i2 = (int)(u32)k2;
    o.w0 = w0 / s; o.w1 = w1 / s; o.w2 = w2 / s;
    kw[b * N2 + (int)n] = o;
  }
}

// ---- K3: interp + concat -> bf16 LDS -> MFMA MLP1 -> MFMA MLP2 -> fp32 out -----
// (unchanged, known-good)
__global__ __launch_bounds__(256) void interp_mlp(
    const float* __restrict__ in0, const float* __restrict__ in1,
    const KW* __restrict__ kw,
    const u16* __restrict__ W1t, const float* __restrict__ b1,
    const u16* __restrict__ W2t, const float* __restrict__ b2,
    float* __restrict__ out) {
  __shared__ __align__(16) u16 xs[4][16][PADX];   // 25,600 B
  __shared__ __align__(16) u16 hs[4][16][PADH];   // 17,408 B
  int t = threadIdx.x;
  int wave = t >> 6, lane = t & 63;
  int l16 = lane & 15, quad = lane >> 4;
  int qbase = blockIdx.x * 64 + wave * 16;
  int b = qbase >> 15;                  // uniform per block

  for (int qi = 0; qi < 16; qi++) {
    int q = qbase + qi;
    KW k = kw[q];                       // wave-uniform load
    const float* base = in0 + (size_t)b * N1 * ROW0 + 3;
    const float* r0 = base + (size_t)k.i0 * ROW0;
    const float* r1 = base + (size_t)k.i1 * ROW0;
    const float* r2 = base + (size_t)k.i2 * ROW0;
    float lo = __fadd_rn(__fadd_rn(__fmul_rn(k.w0, r0[lane]),
                                   __fmul_rn(k.w1, r1[lane])),
                         __fmul_rn(k.w2, r2[lane]));
    float hi = __fadd_rn(__fadd_rn(__fmul_rn(k.w0, r0[64 + lane]),
                                   __fmul_rn(k.w1, r1[64 + lane])),
                         __fmul_rn(k.w2, r2[64 + lane]));
    xs[wave][qi][lane]      = f2bf(lo);
    xs[wave][qi][64 + lane] = f2bf(hi);
    int n2 = q & (N2 - 1);              // channels 128..191 = points2
    xs[wave][qi][C1 + lane] = f2bf(in1[(size_t)(b * N2 + n2) * ROW1 + 3 + lane]);
  }
  __syncthreads();

  float4_ acc[8];
#pragma unroll
  for (int nt = 0; nt < 8; nt++) acc[nt] = (float4_)0.f;
#pragma unroll
  for (int k0 = 0; k0 < CIN; k0 += 32) {
    short8 af = *(const short8*)&xs[wave][l16][k0 + quad * 8];
#pragma unroll
    for (int nt = 0; nt < 8; nt++) {
      short8 bf = *(const short8*)(W1t + (size_t)(nt * 16 + l16) * CIN + k0 + quad * 8);
      acc[nt] = __builtin_amdgcn_mfma_f32_16x16x32_bf16(af, bf, acc[nt], 0, 0, 0);
    }
  }
#pragma unroll
  for (int nt = 0; nt < 8; nt++) {
    float bv = b1[nt * 16 + l16];
#pragma unroll
    for (int r = 0; r < 4; r++) {   // C/D: row=quad*4+r, col=nt*16+l16
      hs[wave][quad * 4 + r][nt * 16 + l16] = f2bf(fmaxf(acc[nt][r] + bv, 0.f));
    }
  }
  __syncthreads();

  float4_ a2[8];
#pragma unroll
  for (int nt = 0; nt < 8; nt++) a2[nt] = (float4_)0.f;
#pragma unroll
  for (int k0 = 0; k0 < F1; k0 += 32) {
    short8 af = *(const short8*)&hs[wave][l16][k0 + quad * 8];
#pragma unroll
    for (int nt = 0; nt < 8; nt++) {
      short8 bf = *(const short8*)(W2t + (size_t)(nt * 16 + l16) * F1 + k0 + quad * 8);
      a2[nt] = __builtin_amdgcn_mfma_f32_16x16x32_bf16(af, bf, a2[nt], 0, 0, 0);
    }
  }
#pragma unroll
  for (int nt = 0; nt < 8; nt++) {
    float bv = b2[nt * 16 + l16];
#pragma unroll
    for (int r = 0; r < 4; r++) {
      int row = qbase + quad * 4 + r;
      out[(size_t)row * F2 + nt * 16 + l16] = fmaxf(a2[nt][r] + bv, 0.f);
    }
  }
}

extern "C" void kernel_launch(void* const* d_in, const int* in_sizes, int n_in,
                              void* d_out, int out_size, void* d_ws, size_t ws_size,
                              hipStream_t stream) {
  const float *in0 = nullptr, *in1 = nullptr, *W1 = nullptr, *W2 = nullptr;
  const float *b1 = nullptr, *b2 = nullptr;
  for (int i = 0; i < n_in; i++) {
    const float* p = (const float*)d_in[i];
    switch (in_sizes[i]) {
      case 2 * N1 * ROW0: in0 = p; break;
      case 2 * N2 * ROW1: in1 = p; break;
      case CIN * F1:      W1  = p; break;
      case F1 * F2:       W2  = p; break;
      case F1:            (b1 ? b2 : b1) = p; break;
      default: break;
    }
  }
  if (!in0) in0 = (const float*)d_in[0];
  if (!in1) in1 = (const float*)d_in[1];
  if (!W1)  W1  = (const float*)d_in[2];
  if (!b1)  b1  = (const float*)d_in[3];
  if (!W2)  W2  = (const float*)d_in[4];
  if (!b2)  b2  = (const float*)d_in[5];

  float* out = (float*)d_out;   // fp32: x (65536*128) ++ xyz2 (65536*3)

  // ws layout (11.22 MB < proven 13.58 MB):
  //   W1t 49,152 | W2t 32,768 | kw 1,572,864 | cstart 2,097,160 | qstart 2,097,160
  //   | ccursor 2,097,152 | qcursor 2,097,152 (adjacent -> one memset)
  //   | xyzs 131,072 | qxyz 1,048,576
  char* ws = (char*)d_ws;
  u16*    W1t    = (u16*)(ws + 0);
  u16*    W2t    = (u16*)(ws + 49152);
  KW*     kw     = (KW*)(ws + 81920);
  int*    cstart = (int*)(ws + 1654784);
  int*    qstart = (int*)(ws + 3751944);
  int*    ccur   = (int*)(ws + 5849104);
  int*    qcur   = (int*)(ws + 7946256);
  float4* xyzs   = (float4*)(ws + 10043408);
  float4* qxyz   = (float4*)(ws + 10174480);

  hipMemsetAsync(ccur, 0, (size_t)2 * NB * NC * 4, stream);   // ccur+qcur
  repack_cnt<<<dim3(256), dim3(256), 0, stream>>>(W1, W2, W1t, W2t, in0, in1, ccur, qcur);
  grid_scan<<<dim3(4), dim3(1024), 0, stream>>>(ccur, cstart, qcur, qstart);
  scatter_all<<<dim3(288), dim3(256), 0, stream>>>(in0, in1, ccur, qcur, xyzs, qxyz, out);
  knn_grid<<<dim3(NQ * 4 / 256), dim3(256), 0, stream>>>(cstart, xyzs, qxyz, kw);
  interp_mlp<<<dim3(NQ / 64), dim3(256), 0, stream>>>(in0, in1, kw, W1t, b1, W2t, b2, out);
}

// Round 9
// 1542.714 us; speedup vs baseline: 1.6343x; 1.1532x over previous
//
#include <hip/hip_runtime.h>
#include <cfloat>

typedef unsigned short u16;
typedef unsigned int   u32;
typedef unsigned long long u64;
typedef __attribute__((ext_vector_type(8))) short short8;
typedef __attribute__((ext_vector_type(4))) float float4_;

#define NB   2
#define N1   4096
#define N2   32768
#define C1   128
#define C2   64
#define CIN  192      // C1 + C2
#define F1   128
#define F2   128
#define ROW0 131      // 3 + C1 (fp32)
#define ROW1 67       // 3 + C2 (fp32)
#define NQ   (NB * N2)   // 65536 total query points
#define EPSF 1e-07f
#define PADX 200      // LDS x-tile pitch (u16)
#define PADH 136      // LDS h-tile pitch (u16)

// ---- spatial grid: 64^3 cells over [-8,8]^3 (exactness validated R7/R8) ------
#define G     64
#define NC    (G * G * G)       // 262144 cells per batch
#define GLO   (-8.0f)
#define GH    0.25f
#define GHINV 4.0f
#define SCH   (NC / 1024)       // 256 cells per scan thread
#define NWKNN 8192              // knn worker waves (2048 blocks x 4)

// round-to-nearest-even fp32 -> bf16 (finite data only)
__device__ __forceinline__ u16 f2bf(float f) {
  u32 x = __float_as_uint(f);
  return (u16)((x + 0x7fffu + ((x >> 16) & 1u)) >> 16);
}

struct KW { int i0, i1, i2; float w0, w1, w2; };   // 24 B

// u64 key = (d_bits<<32)|idx : one u64 compare == lexicographic (d, idx) ==
// lax.top_k's tie rule. Scan-order independent; inserts of certified-far
// points are no-ops. (Validated R7/R8.)
__device__ __forceinline__ void kins(u64 k, u64& k0, u64& k1, u64& k2) {
  bool lt0 = k < k0, lt1 = k < k1, lt2 = k < k2;
  k2 = lt1 ? k1 : (lt2 ? k : k2);
  k1 = lt0 ? k0 : (lt1 ? k : k1);
  k0 = lt0 ? k  : k0;
}

__device__ __forceinline__ void cell_coords(float x, float y, float z,
                                            int& cx, int& cy, int& cz) {
  cx = (int)((x - GLO) * GHINV); cx = cx < 0 ? 0 : (cx > G - 1 ? G - 1 : cx);
  cy = (int)((y - GLO) * GHINV); cy = cy < 0 ? 0 : (cy > G - 1 ? G - 1 : cy);
  cz = (int)((z - GLO) * GHINV); cz = cz < 0 ? 0 : (cz > G - 1 ? G - 1 : cz);
}

// ---- repack weights + count candidates AND queries per grid cell --------------
__global__ void repack_cnt(const float* __restrict__ W1, const float* __restrict__ W2,
                           u16* __restrict__ W1t, u16* __restrict__ W2t,
                           const float* __restrict__ in0, const float* __restrict__ in1,
                           int* __restrict__ ccnt, int* __restrict__ qcnt) {
  int i = blockIdx.x * 256 + threadIdx.x;
  if (i < F1 * CIN) { int n = i / CIN, k = i % CIN; W1t[i] = f2bf(W1[k * F1 + n]); }
  if (i < F2 * F1)  { int n = i / F1,  k = i % F1;  W2t[i] = f2bf(W2[k * F2 + n]); }
  if (i < NB * N1) {
    const float* r = in0 + (size_t)i * ROW0;
    int b = i >> 12;
    int cx, cy, cz; cell_coords(r[0], r[1], r[2], cx, cy, cz);
    atomicAdd(&ccnt[b * NC + ((cz << 12) | (cy << 6) | cx)], 1);
  }
  if (i < NB * N2) {
    int b = i >> 15, n = i & (N2 - 1);
    const float* r = in1 + (size_t)(b * N2 + n) * ROW1;
    int cx, cy, cz; cell_coords(r[0], r[1], r[2], cx, cy, cz);
    atomicAdd(&qcnt[b * NC + ((cz << 12) | (cy << 6) | cx)], 1);
  }
}

// ---- exclusive scan -> starts + cursor; query pass appends occupied cells to
// the worklist (order nondeterministic; results order-independent). ------------
__global__ __launch_bounds__(1024) void grid_scan(int* __restrict__ ccnt,
                                                  int* __restrict__ cstart,
                                                  int* __restrict__ qcnt,
                                                  int* __restrict__ qstart,
                                                  int* __restrict__ wl,
                                                  int* __restrict__ wlcnt) {
  int b = blockIdx.x & 1, which = blockIdx.x >> 1, t = threadIdx.x;
  int* cnt = (which ? qcnt : ccnt) + b * NC;
  int* cs  = (which ? qstart : cstart) + b * (NC + 1);
  __shared__ int ps[1024];
  int base = t * SCH;
  int sum = 0;
  for (int k = 0; k < SCH; k++) sum += cnt[base + k];
  ps[t] = sum; __syncthreads();
  for (int off = 1; off < 1024; off <<= 1) {   // Hillis-Steele inclusive
    int v = (t >= off) ? ps[t - off] : 0; __syncthreads();
    ps[t] += v; __syncthreads();
  }
  int run = ps[t] - sum;                        // exclusive offset
  for (int k = 0; k < SCH; k++) {
    int s = cnt[base + k];
    cs[base + k] = run; cnt[base + k] = run;    // cursor := start
    if (which && s > 0) {                       // occupied query cell -> worklist
      int pos = atomicAdd(wlcnt, 1);
      wl[pos] = (b << 18) | (base + k);
    }
    run += s;
  }
  if (t == 1023) cs[NC] = run;
}

// ---- scatter candidates + queries into cell-sorted order; xyz2 passthrough ----
__global__ void scatter_all(const float* __restrict__ in0, const float* __restrict__ in1,
                            int* __restrict__ ccur, int* __restrict__ qcur,
                            float4* __restrict__ xyzs, float4* __restrict__ qxyz,
                            float* __restrict__ out) {
  int i = blockIdx.x * 256 + threadIdx.x;
  if (i < NB * N1) {
    const float* r = in0 + (size_t)i * ROW0;
    float x = r[0], y = r[1], z = r[2];
    int b = i >> 12, pi = i & (N1 - 1);
    int cx, cy, cz; cell_coords(x, y, z, cx, cy, cz);
    int pos = atomicAdd(&ccur[b * NC + ((cz << 12) | (cy << 6) | cx)], 1);
    float4 v; v.x = x; v.y = y; v.z = z; v.w = __uint_as_float((u32)pi);
    xyzs[b * N1 + pos] = v;
  } else if (i < NB * N1 + NB * N2) {
    int j = i - NB * N1;
    int b = j >> 15, n = j & (N2 - 1);
    const float* r = in1 + (size_t)(b * N2 + n) * ROW1;
    float x = r[0], y = r[1], z = r[2];
    float* o = out + (size_t)NQ * F2 + (size_t)(b * N2 + n) * 3;  // passthrough
    o[0] = x; o[1] = y; o[2] = z;
    int cx, cy, cz; cell_coords(x, y, z, cx, cy, cz);
    int pos = atomicAdd(&qcur[b * NC + ((cz << 12) | (cy << 6) | cx)], 1);
    float4 v; v.x = x; v.y = y; v.z = z; v.w = __uint_as_float((u32)n);
    qxyz[b * N2 + pos] = v;
  }
}

// wave-uniform cell scan: s/e/addresses all scalar (derive from SGPR entry);
// every lane inserts every point into its OWN top-3 (per-lane query).
__device__ __forceinline__ void scan_cell_u(int x, int y, int z,
    const int* __restrict__ csb, const float4* __restrict__ xp,
    float qx, float qy, float qz, u64& k0, u64& k1, u64& k2) {
  if ((unsigned)x >= G || (unsigned)y >= G || (unsigned)z >= G) return;
  int c = (z << 12) | (y << 6) | x;
  int s = csb[c], e = csb[c + 1];               // uniform -> s_load
  for (int j = s; j < e; ++j) {
    float4 pt = xp[j];                          // uniform -> s_load broadcast
    float dx = qx - pt.x, dy = qy - pt.y, dz = qz - pt.z;
    float d = __fadd_rn(__fadd_rn(__fmul_rn(dx, dx), __fmul_rn(dy, dy)),
                        __fmul_rn(dz, dz));     // exact reference order
    u64 k = ((u64)__float_as_uint(d) << 32) | (u32)__float_as_uint(pt.w);
    kins(k, k0, k1, k2);
  }
}

// ---- kNN: one WAVE per occupied query cell ------------------------------------
// Lanes hold that cell's queries (chunks of 64 if more). Ring enumeration is
// wave-uniform (scalar loads, one fetch per cell for all lanes); each lane
// sees ALL scanned points -> per-lane certification, no merge needed.
// Certificate (validated R7/R8): m = dist(q, searched-cube boundary) - 1e-5;
// stop when m>0 && m*m>d2. Loop to r=G covers the whole grid -> exact even
// when certification never fires.
__global__ __launch_bounds__(256) void knn_cell(
    const int* __restrict__ cstart, const float4* __restrict__ xyzs,
    const int* __restrict__ qstart, const float4* __restrict__ qxyz,
    const int* __restrict__ wl, const int* __restrict__ wlcnt,
    KW* __restrict__ kw) {
  int lane = threadIdx.x & 63;
  int gw = (blockIdx.x * 256 + threadIdx.x) >> 6;   // global wave id
  int nwork = wlcnt[0];
  for (int w = gw; w < nwork; w += NWKNN) {
    int entry = __builtin_amdgcn_readfirstlane(wl[w]);
    int b = entry >> 18, c = entry & (NC - 1);
    int cx = c & 63, cy = (c >> 6) & 63, cz = c >> 12;
    const int*    csb = cstart + b * (NC + 1);
    const int*    qsb = qstart + b * (NC + 1);
    const float4* xp  = xyzs + b * N1;
    int qs0 = qsb[c], qe = qsb[c + 1];              // uniform
    for (int q0 = qs0; q0 < qe; q0 += 64) {         // chunks (rarely >1)
      int qi = q0 + lane;
      bool active = qi < qe;
      float4 qv = qxyz[b * N2 + (active ? qi : qe - 1)];
      float qx = qv.x, qy = qv.y, qz = qv.z;
      u32 n = __float_as_uint(qv.w);
      u64 k0 = 0x7F800000FFFFFFFFull, k1 = k0, k2 = k0;   // (inf, idx_max)
      bool done = !active;
      for (int r = 0; r <= G; ++r) {
        if (r == 0) {
          scan_cell_u(cx, cy, cz, csb, xp, qx, qy, qz, k0, k1, k2);
        } else {
          for (int dz = -r; dz <= r; dz += 2 * r)          // faces dz = +-r
            for (int dy = -r; dy <= r; ++dy)
              for (int dx = -r; dx <= r; ++dx)
                scan_cell_u(cx + dx, cy + dy, cz + dz, csb, xp, qx, qy, qz, k0, k1, k2);
          for (int dz = -r + 1; dz <= r - 1; ++dz) {       // interior slabs
            for (int dy = -r; dy <= r; dy += 2 * r)        // rows dy = +-r
              for (int dx = -r; dx <= r; ++dx)
                scan_cell_u(cx + dx, cy + dy, cz + dz, csb, xp, qx, qy, qz, k0, k1, k2);
            for (int dx = -r; dx <= r; dx += 2 * r)        // cols dx = +-r
              for (int dy = -r + 1; dy <= r - 1; ++dy)
                scan_cell_u(cx + dx, cy + dy, cz + dz, csb, xp, qx, qy, qz, k0, k1, k2);
          }
        }
        float lox = GLO + (float)(cx - r) * GH, hix = GLO + (float)(cx + r + 1) * GH;
        float loy = GLO + (float)(cy - r) * GH, hiy = GLO + (float)(cy + r + 1) * GH;
        float loz = GLO + (float)(cz - r) * GH, hiz = GLO + (float)(cz + r + 1) * GH;
        float m = fminf(fminf(fminf(qx - lox, hix - qx), fminf(qy - loy, hiy - qy)),
                        fminf(qz - loz, hiz - qz)) - 1e-5f;   // margin >> fp slop
        float d2f = __uint_as_float((u32)(k2 >> 32));
        done = done || ((m > 0.f) && (__fmul_rn(m, m) > d2f));
        if (__ballot(!done) == 0ull) break;               // wave-uniform
      }
      if (active) {
        float d0 = __uint_as_float((u32)(k0 >> 32));
        float d1 = __uint_as_float((u32)(k1 >> 32));
        float d2 = __uint_as_float((u32)(k2 >> 32));
        float a0 = fmaxf(d0, EPSF), a1 = fmaxf(d1, EPSF), a2 = fmaxf(d2, EPSF);
        float w0 = 1.f / a0, w1 = 1.f / a1, w2 = 1.f / a2;
        float s = __fadd_rn(__fadd_rn(w0, w1), w2);
        KW o; o.i0 = (int)(u32)k0; o.i1 = (int)(u32)k1; o.i2 = (int)(u32)k2;
        o.w0 = w0 / s; o.w1 = w1 / s; o.w2 = w2 / s;
        kw[b * N2 + (int)n] = o;
      }
    }
  }
}

// ---- K3: interp + concat -> bf16 LDS -> MFMA MLP1 -> MFMA MLP2 -> fp32 out -----
// (unchanged, known-good)
__global__ __launch_bounds__(256) void interp_mlp(
    const float* __restrict__ in0, const float* __restrict__ in1,
    const KW* __restrict__ kw,
    const u16* __restrict__ W1t, const float* __restrict__ b1,
    const u16* __restrict__ W2t, const float* __restrict__ b2,
    float* __restrict__ out) {
  __shared__ __align__(16) u16 xs[4][16][PADX];   // 25,600 B
  __shared__ __align__(16) u16 hs[4][16][PADH];   // 17,408 B
  int t = threadIdx.x;
  int wave = t >> 6, lane = t & 63;
  int l16 = lane & 15, quad = lane >> 4;
  int qbase = blockIdx.x * 64 + wave * 16;
  int b = qbase >> 15;                  // uniform per block

  for (int qi = 0; qi < 16; qi++) {
    int q = qbase + qi;
    KW k = kw[q];                       // wave-uniform load
    const float* base = in0 + (size_t)b * N1 * ROW0 + 3;
    const float* r0 = base + (size_t)k.i0 * ROW0;
    const float* r1 = base + (size_t)k.i1 * ROW0;
    const float* r2 = base + (size_t)k.i2 * ROW0;
    float lo = __fadd_rn(__fadd_rn(__fmul_rn(k.w0, r0[lane]),
                                   __fmul_rn(k.w1, r1[lane])),
                         __fmul_rn(k.w2, r2[lane]));
    float hi = __fadd_rn(__fadd_rn(__fmul_rn(k.w0, r0[64 + lane]),
                                   __fmul_rn(k.w1, r1[64 + lane])),
                         __fmul_rn(k.w2, r2[64 + lane]));
    xs[wave][qi][lane]      = f2bf(lo);
    xs[wave][qi][64 + lane] = f2bf(hi);
    int n2 = q & (N2 - 1);              // channels 128..191 = points2
    xs[wave][qi][C1 + lane] = f2bf(in1[(size_t)(b * N2 + n2) * ROW1 + 3 + lane]);
  }
  __syncthreads();

  float4_ acc[8];
#pragma unroll
  for (int nt = 0; nt < 8; nt++) acc[nt] = (float4_)0.f;
#pragma unroll
  for (int k0 = 0; k0 < CIN; k0 += 32) {
    short8 af = *(const short8*)&xs[wave][l16][k0 + quad * 8];
#pragma unroll
    for (int nt = 0; nt < 8; nt++) {
      short8 bf = *(const short8*)(W1t + (size_t)(nt * 16 + l16) * CIN + k0 + quad * 8);
      acc[nt] = __builtin_amdgcn_mfma_f32_16x16x32_bf16(af, bf, acc[nt], 0, 0, 0);
    }
  }
#pragma unroll
  for (int nt = 0; nt < 8; nt++) {
    float bv = b1[nt * 16 + l16];
#pragma unroll
    for (int r = 0; r < 4; r++) {   // C/D: row=quad*4+r, col=nt*16+l16
      hs[wave][quad * 4 + r][nt * 16 + l16] = f2bf(fmaxf(acc[nt][r] + bv, 0.f));
    }
  }
  __syncthreads();

  float4_ a2[8];
#pragma unroll
  for (int nt = 0; nt < 8; nt++) a2[nt] = (float4_)0.f;
#pragma unroll
  for (int k0 = 0; k0 < F1; k0 += 32) {
    short8 af = *(const short8*)&hs[wave][l16][k0 + quad * 8];
#pragma unroll
    for (int nt = 0; nt < 8; nt++) {
      short8 bf = *(const short8*)(W2t + (size_t)(nt * 16 + l16) * F1 + k0 + quad * 8);
      a2[nt] = __builtin_amdgcn_mfma_f32_16x16x32_bf16(af, bf, a2[nt], 0, 0, 0);
    }
  }
#pragma unroll
  for (int nt = 0; nt < 8; nt++) {
    float bv = b2[nt * 16 + l16];
#pragma unroll
    for (int r = 0; r < 4; r++) {
      int row = qbase + quad * 4 + r;
      out[(size_t)row * F2 + nt * 16 + l16] = fmaxf(a2[nt][r] + bv, 0.f);
    }
  }
}

extern "C" void kernel_launch(void* const* d_in, const int* in_sizes, int n_in,
                              void* d_out, int out_size, void* d_ws, size_t ws_size,
                              hipStream_t stream) {
  const float *in0 = nullptr, *in1 = nullptr, *W1 = nullptr, *W2 = nullptr;
  const float *b1 = nullptr, *b2 = nullptr;
  for (int i = 0; i < n_in; i++) {
    const float* p = (const float*)d_in[i];
    switch (in_sizes[i]) {
      case 2 * N1 * ROW0: in0 = p; break;
      case 2 * N2 * ROW1: in1 = p; break;
      case CIN * F1:      W1  = p; break;
      case F1 * F2:       W2  = p; break;
      case F1:            (b1 ? b2 : b1) = p; break;
      default: break;
    }
  }
  if (!in0) in0 = (const float*)d_in[0];
  if (!in1) in1 = (const float*)d_in[1];
  if (!W1)  W1  = (const float*)d_in[2];
  if (!b1)  b1  = (const float*)d_in[3];
  if (!W2)  W2  = (const float*)d_in[4];
  if (!b2)  b2  = (const float*)d_in[5];

  float* out = (float*)d_out;   // fp32: x (65536*128) ++ xyz2 (65536*3)

  // ws layout (11.49 MB < proven 13.58 MB):
  //   W1t 49,152 | W2t 32,768 | kw 1,572,864 | cstart 2,097,160 | qstart 2,097,160
  //   | ccur 2,097,152 | qcur 2,097,152 | wlcnt 16 | wl 262,144
  //   | xyzs 131,072 | qxyz 1,048,576
  char* ws = (char*)d_ws;
  u16*    W1t    = (u16*)(ws + 0);
  u16*    W2t    = (u16*)(ws + 49152);
  KW*     kw     = (KW*)(ws + 81920);
  int*    cstart = (int*)(ws + 1654784);
  int*    qstart = (int*)(ws + 3751944);
  int*    ccur   = (int*)(ws + 5849104);
  int*    qcur   = (int*)(ws + 7946256);
  int*    wlcnt  = (int*)(ws + 10043408);
  int*    wl     = (int*)(ws + 10043424);
  float4* xyzs   = (float4*)(ws + 10305568);
  float4* qxyz   = (float4*)(ws + 10436640);

  // one memset covers ccur + qcur + wlcnt (contiguous)
  hipMemsetAsync(ccur, 0, (size_t)(10043424 - 5849104), stream);
  repack_cnt<<<dim3(256), dim3(256), 0, stream>>>(W1, W2, W1t, W2t, in0, in1, ccur, qcur);
  grid_scan<<<dim3(4), dim3(1024), 0, stream>>>(ccur, cstart, qcur, qstart, wl, wlcnt);
  scatter_all<<<dim3(288), dim3(256), 0, stream>>>(in0, in1, ccur, qcur, xyzs, qxyz, out);
  knn_cell<<<dim3(NWKNN / 4), dim3(256), 0, stream>>>(cstart, xyzs, qstart, qxyz, wl, wlcnt, kw);
  interp_mlp<<<dim3(NQ / 64), dim3(256), 0, stream>>>(in0, in1, kw, W1t, b1, W2t, b2, out);
}

// Round 10
// 266.481 us; speedup vs baseline: 9.4615x; 5.7892x over previous
//
#include <hip/hip_runtime.h>
#include <cfloat>

typedef unsigned short u16;
typedef unsigned int   u32;
typedef __attribute__((ext_vector_type(8))) short short8;
typedef __attribute__((ext_vector_type(4))) float float4_;

#define NB   2
#define N1   4096
#define N2   32768
#define C1   128
#define C2   64
#define CIN  192      // C1 + C2
#define F1   128
#define F2   128
#define ROW0 131      // 3 + C1 (fp32)
#define ROW1 67       // 3 + C2 (fp32)
#define NQ   (NB * N2)   // 65536 total query points
#define EPSF 1e-07f
#define KSPLIT 8
#define KCH  (N1 / KSPLIT)   // 512 candidates per tile
#define PADX 200      // LDS x-tile pitch (u16)
#define PADH 136      // LDS h-tile pitch (u16)

// round-to-nearest-even fp32 -> bf16 (finite data only)
__device__ __forceinline__ u16 f2bf(float f) {
  u32 x = __float_as_uint(f);
  return (u16)((x + 0x7fffu + ((x >> 16) & 1u)) >> 16);
}

// BRANCHLESS stable top-3 insert (merge path only). Strict <: earlier index wins.
__device__ __forceinline__ void ins3b(float d, int gi,
    float& d0, float& d1, float& d2, int& i0, int& i1, int& i2) {
  bool lt0 = d < d0, lt1 = d < d1, lt2 = d < d2;
  d2 = lt1 ? d1 : (lt2 ? d : d2);
  i2 = lt1 ? i1 : (lt2 ? gi : i2);
  d1 = lt0 ? d0 : (lt1 ? d : d1);
  i1 = lt0 ? i0 : (lt1 ? gi : i1);
  d0 = lt0 ? d : d0;
  i0 = lt0 ? gi : i0;
}

struct Part { float d0, d1, d2; int i0, i1, i2; };   // 24 B
struct KW   { int i0, i1, i2; float w0, w1, w2; };   // 24 B

// ---- repack: weights fp32 -> transposed bf16; candidate xyz -> packed float4 ---
__global__ void repack_w(const float* __restrict__ W1, const float* __restrict__ W2,
                         u16* __restrict__ W1t, u16* __restrict__ W2t,
                         const float* __restrict__ in0, float4* __restrict__ xyz1p) {
  int i = blockIdx.x * 256 + threadIdx.x;
  if (i < F1 * CIN) { int n = i / CIN, k = i % CIN; W1t[i] = f2bf(W1[k * F1 + n]); }
  if (i < F2 * F1)  { int n = i / F1,  k = i % F1;  W2t[i] = f2bf(W2[k * F2 + n]); }
  if (i < NB * N1)  {
    const float* r = in0 + (size_t)i * ROW0;
    xyz1p[i] = make_float4(r[0], r[1], r[2], 0.f);
  }
}

// ---- K1: kNN partial top-3, 512-candidate tile, exact 20-VALU inner loop -------
// (PROVEN R4 kernel: 124 us, issue-bound at the branchless-insert floor.)
// grid (NQ/256, KSPLIT) = 2048 blocks -> 8 blocks/CU, 32 waves/CU.
// Candidates from SGPRs (uniform s_load). Inner loop forced via inline asm:
// 8 dist (RN, exact ref order) + 3 v_cmp_nlt + 5 v_cndmask (all-VGPR + vcc;
// cndmask's vcc read occupies the constant bus -> gi must be VGPR) + min/med3
// value network + 1 v_mov. Also writes xyz2 passthrough from ct==0 blocks.
__global__ __launch_bounds__(256) void knn_part(const float4* __restrict__ xyz1p,
                                                const float* __restrict__ in1,
                                                Part* __restrict__ part,
                                                float* __restrict__ out) {
  int t = threadIdx.x;
  int bb = blockIdx.x >> 7;                   // batch: uniform, threadIdx-free
  int ct = blockIdx.y;
  int c0 = ct * KCH;
  const float4* __restrict__ src = xyz1p + (size_t)bb * N1 + c0;  // uniform base
  int q = blockIdx.x * 256 + t;
  int n = q & (N2 - 1);
  const float* qr = in1 + (size_t)(bb * N2 + n) * ROW1;
  float qx = qr[0], qy = qr[1], qz = qr[2];
  if (ct == 0) {                              // xyz2 passthrough
    float* o = out + (size_t)NQ * F2 + (size_t)q * 3;
    o[0] = qx; o[1] = qy; o[2] = qz;
  }
  float d0 = FLT_MAX, d1 = FLT_MAX, d2 = FLT_MAX;
  int   i0 = 0, i1 = 0, i2 = 0;
#pragma unroll 8
  for (int j = 0; j < KCH; j++) {
    float4 cc = src[j];                       // uniform -> s_load (SGPR broadcast)
    int gi = c0 + j;                          // scalar; "v" constraint -> v_mov
    float dx, dy, dz, vd; int tm;
    asm("v_subrev_f32 %[dx], %[cx], %[qx]\n\t"      // dx = qx - cx
        "v_subrev_f32 %[dy], %[cy], %[qy]\n\t"
        "v_subrev_f32 %[dz], %[cz], %[qz]\n\t"
        "v_mul_f32 %[dx], %[dx], %[dx]\n\t"
        "v_mul_f32 %[dy], %[dy], %[dy]\n\t"
        "v_mul_f32 %[dz], %[dz], %[dz]\n\t"
        "v_add_f32 %[dx], %[dx], %[dy]\n\t"         // (dx^2 + dy^2)
        "v_add_f32 %[vd], %[dx], %[dz]\n\t"         // + dz^2  (exact ref order)
        "v_cmp_nlt_f32 vcc, %[vd], %[d2]\n\t"       // vcc = !(d<d2)
        "v_cndmask_b32 %[tm], %[gi], %[i2], vcc\n\t"  // t2 = lt2 ? gi : i2
        "v_cmp_nlt_f32 vcc, %[vd], %[d1]\n\t"       // vcc = !(d<d1)
        "v_cndmask_b32 %[i2], %[i1], %[tm], vcc\n\t"  // i2 = lt1 ? i1 : t2
        "v_cndmask_b32 %[tm], %[gi], %[i1], vcc\n\t"  // t1 = lt1 ? gi : i1
        "v_cmp_nlt_f32 vcc, %[vd], %[d0]\n\t"       // vcc = !(d<d0)
        "v_cndmask_b32 %[i1], %[i0], %[tm], vcc\n\t"  // i1 = lt0 ? i0 : t1
        "v_cndmask_b32 %[i0], %[gi], %[i0], vcc\n\t"  // i0 = lt0 ? gi : i0
        "v_med3_f32 %[d2], %[vd], %[d1], %[d2]\n\t"   // nd2 (uses old d1,d2)
        "v_med3_f32 %[d1], %[d0], %[vd], %[d1]\n\t"   // nd1 (uses old d0,d1)
        "v_min_f32 %[d0], %[vd], %[d0]"               // nd0
        : [d0]"+v"(d0), [d1]"+v"(d1), [d2]"+v"(d2),
          [i0]"+v"(i0), [i1]"+v"(i1), [i2]"+v"(i2),
          [dx]"=&v"(dx), [dy]"=&v"(dy), [dz]"=&v"(dz),
          [vd]"=&v"(vd), [tm]"=&v"(tm)
        : [qx]"v"(qx), [qy]"v"(qy), [qz]"v"(qz),
          [cx]"s"(cc.x), [cy]"s"(cc.y), [cz]"s"(cc.z), [gi]"v"(gi)
        : "vcc");
  }
  Part p; p.d0 = d0; p.d1 = d1; p.d2 = d2; p.i0 = i0; p.i1 = i1; p.i2 = i2;
  part[((size_t)q << 3) + ct] = p;
}

// ---- K2: merge partials (ascending tile order preserves tie stability) ---------
__global__ __launch_bounds__(256) void knn_merge(const Part* __restrict__ part,
                                                 KW* __restrict__ kw) {
  int q = blockIdx.x * 256 + threadIdx.x;
  float d0 = FLT_MAX, d1 = FLT_MAX, d2 = FLT_MAX;
  int   i0 = 0, i1 = 0, i2 = 0;
#pragma unroll
  for (int ct = 0; ct < KSPLIT; ct++) {
    Part p = part[((size_t)q << 3) + ct];
    ins3b(p.d0, p.i0, d0, d1, d2, i0, i1, i2);
    ins3b(p.d1, p.i1, d0, d1, d2, i0, i1, i2);
    ins3b(p.d2, p.i2, d0, d1, d2, i0, i1, i2);
  }
  float a0 = fmaxf(d0, EPSF), a1 = fmaxf(d1, EPSF), a2 = fmaxf(d2, EPSF);
  float w0 = 1.f / a0, w1 = 1.f / a1, w2 = 1.f / a2;
  float s = __fadd_rn(__fadd_rn(w0, w1), w2);
  KW o; o.i0 = i0; o.i1 = i1; o.i2 = i2;
  o.w0 = w0 / s; o.w1 = w1 / s; o.w2 = w2 / s;
  kw[q] = o;
}

// ---- K3: interp + concat -> bf16 LDS -> MFMA MLP1 -> MFMA MLP2 -> fp32 out -----
// block = 256 = 4 waves; each wave owns 16 query rows. 1024 blocks.
// GATHER RESTRUCTURED (this round): the old loop had a serial per-query chain
// kw-load -> addr -> 7 gathers (16 chained L2 round-trips/wave). Now all 16 kw
// loads are hoisted and issued up-front; the fully-unrolled gather loop's 112
// row/points2 loads then pipeline (memory-level parallelism) as kws land.
__global__ __launch_bounds__(256) void interp_mlp(
    const float* __restrict__ in0, const float* __restrict__ in1,
    const KW* __restrict__ kw,
    const u16* __restrict__ W1t, const float* __restrict__ b1,
    const u16* __restrict__ W2t, const float* __restrict__ b2,
    float* __restrict__ out) {
  __shared__ __align__(16) u16 xs[4][16][PADX];   // 25,600 B
  __shared__ __align__(16) u16 hs[4][16][PADH];   // 17,408 B
  int t = threadIdx.x;
  int wave = t >> 6, lane = t & 63;
  int l16 = lane & 15, quad = lane >> 4;
  int qbase = blockIdx.x * 64 + wave * 16;
  int b = qbase >> 15;                  // uniform per block
  const float* base   = in0 + (size_t)b * N1 * ROW0 + 3;
  const float* p2base = in1 + (size_t)b * N2 * ROW1 + 3;

  // stage 1: hoist all 16 kw loads (independent, issue back-to-back)
  KW kws[16];
#pragma unroll
  for (int qi = 0; qi < 16; qi++) kws[qi] = kw[qbase + qi];

  // stage 2: unrolled gather; loads across iterations are independent given kws
#pragma unroll
  for (int qi = 0; qi < 16; qi++) {
    const float* r0 = base + (size_t)kws[qi].i0 * ROW0;
    const float* r1 = base + (size_t)kws[qi].i1 * ROW0;
    const float* r2 = base + (size_t)kws[qi].i2 * ROW0;
    float a0 = r0[lane],      a1 = r1[lane],      a2 = r2[lane];
    float c0 = r0[64 + lane], c1 = r1[64 + lane], c2 = r2[64 + lane];
    int n2 = (qbase + qi) & (N2 - 1);
    float p2 = p2base[(size_t)n2 * ROW1 + lane];
    float w0 = kws[qi].w0, w1 = kws[qi].w1, w2 = kws[qi].w2;
    float lo = __fadd_rn(__fadd_rn(__fmul_rn(w0, a0), __fmul_rn(w1, a1)),
                         __fmul_rn(w2, a2));
    float hi = __fadd_rn(__fadd_rn(__fmul_rn(w0, c0), __fmul_rn(w1, c1)),
                         __fmul_rn(w2, c2));
    xs[wave][qi][lane]      = f2bf(lo);
    xs[wave][qi][64 + lane] = f2bf(hi);
    xs[wave][qi][C1 + lane] = f2bf(p2);   // channels 128..191 = points2
  }
  __syncthreads();

  // GEMM1: h = relu(x @ W1 + b1); A from LDS, B from global (L1/L2-resident)
  float4_ acc[8];
#pragma unroll
  for (int nt = 0; nt < 8; nt++) acc[nt] = (float4_)0.f;
#pragma unroll
  for (int k0 = 0; k0 < CIN; k0 += 32) {
    short8 af = *(const short8*)&xs[wave][l16][k0 + quad * 8];
#pragma unroll
    for (int nt = 0; nt < 8; nt++) {
      short8 bf = *(const short8*)(W1t + (size_t)(nt * 16 + l16) * CIN + k0 + quad * 8);
      acc[nt] = __builtin_amdgcn_mfma_f32_16x16x32_bf16(af, bf, acc[nt], 0, 0, 0);
    }
  }
#pragma unroll
  for (int nt = 0; nt < 8; nt++) {
    float bv = b1[nt * 16 + l16];
#pragma unroll
    for (int r = 0; r < 4; r++) {   // C/D: row=quad*4+r, col=nt*16+l16
      hs[wave][quad * 4 + r][nt * 16 + l16] = f2bf(fmaxf(acc[nt][r] + bv, 0.f));
    }
  }
  __syncthreads();

  // GEMM2: y = relu(h @ W2 + b2) -> fp32 global store
  float4_ a2[8];
#pragma unroll
  for (int nt = 0; nt < 8; nt++) a2[nt] = (float4_)0.f;
#pragma unroll
  for (int k0 = 0; k0 < F1; k0 += 32) {
    short8 af = *(const short8*)&hs[wave][l16][k0 + quad * 8];
#pragma unroll
    for (int nt = 0; nt < 8; nt++) {
      short8 bf = *(const short8*)(W2t + (size_t)(nt * 16 + l16) * F1 + k0 + quad * 8);
      a2[nt] = __builtin_amdgcn_mfma_f32_16x16x32_bf16(af, bf, a2[nt], 0, 0, 0);
    }
  }
#pragma unroll
  for (int nt = 0; nt < 8; nt++) {
    float bv = b2[nt * 16 + l16];
#pragma unroll
    for (int r = 0; r < 4; r++) {
      int row = qbase + quad * 4 + r;
      out[(size_t)row * F2 + nt * 16 + l16] = fmaxf(a2[nt][r] + bv, 0.f);
    }
  }
}

extern "C" void kernel_launch(void* const* d_in, const int* in_sizes, int n_in,
                              void* d_out, int out_size, void* d_ws, size_t ws_size,
                              hipStream_t stream) {
  // input assignment by element count (ordering-invariant); positional fallback
  const float *in0 = nullptr, *in1 = nullptr, *W1 = nullptr, *W2 = nullptr;
  const float *b1 = nullptr, *b2 = nullptr;
  for (int i = 0; i < n_in; i++) {
    const float* p = (const float*)d_in[i];
    switch (in_sizes[i]) {
      case 2 * N1 * ROW0: in0 = p; break;
      case 2 * N2 * ROW1: in1 = p; break;
      case CIN * F1:      W1  = p; break;
      case F1 * F2:       W2  = p; break;
      case F1:            (b1 ? b2 : b1) = p; break;
      default: break;
    }
  }
  if (!in0) in0 = (const float*)d_in[0];
  if (!in1) in1 = (const float*)d_in[1];
  if (!W1)  W1  = (const float*)d_in[2];
  if (!b1)  b1  = (const float*)d_in[3];
  if (!W2)  W2  = (const float*)d_in[4];
  if (!b2)  b2  = (const float*)d_in[5];

  float* out = (float*)d_out;   // fp32: x (65536*128) ++ xyz2 (65536*3)

  // ws (13.58 MiB, proven): W1t 49,152 | W2t 32,768 | kw 1,572,864 | part 12,582,912
  // xyz1p (131,072) ALIASES the kw region: repack writes it, knn_part reads it,
  // then knn_merge overwrites the region with kw (xyz1p dead by then).
  char* ws = (char*)d_ws;
  u16*    W1t   = (u16*)(ws + 0);
  u16*    W2t   = (u16*)(ws + 49152);
  float4* xyz1p = (float4*)(ws + 81920);      // alias of kw region
  KW*     kw    = (KW*)(ws + 81920);
  Part*   part  = (Part*)(ws + 1654784);

  repack_w<<<dim3(96), dim3(256), 0, stream>>>(W1, W2, W1t, W2t, in0, xyz1p);
  knn_part<<<dim3(NQ / 256, KSPLIT), dim3(256), 0, stream>>>(xyz1p, in1, part, out);
  knn_merge<<<dim3(NQ / 256), dim3(256), 0, stream>>>(part, kw);
  interp_mlp<<<dim3(NQ / 64), dim3(256), 0, stream>>>(in0, in1, kw, W1t, b1, W2t, b2, out);
}